// Round 15
// baseline (566.479 us; speedup 1.0000x reference)
//
#include <hip/hip_runtime.h>
#include <hip/hip_bf16.h>

#define SEQ    4096
#define NBAT   4
#define NHEAD  8
#define NBH    32
#define DMODEL 512
#define DHEAD  64
#define NLM    256
#define NSP    4

typedef __attribute__((ext_vector_type(8))) short s8v;
typedef __attribute__((ext_vector_type(4))) float f4v;

__device__ __forceinline__ float b2f(unsigned short u){
  union { unsigned int i; float f; } v; v.i = ((unsigned int)u) << 16; return v.f;
}
__device__ __forceinline__ unsigned short f2b(float f){
  union { float f; unsigned int i; } v; v.f = f;
  unsigned int r = v.i + 0x7fffu + ((v.i >> 16) & 1u);
  return (unsigned short)(r >> 16);
}
__device__ __forceinline__ s8v ldg8(const unsigned short* p){
  return *reinterpret_cast<const s8v*>(p);
}
__device__ __forceinline__ f4v mfma16(s8v a, s8v b, f4v c){
  return __builtin_amdgcn_mfma_f32_16x16x32_bf16(a, b, c, 0, 0, 0);
}
__device__ __forceinline__ f4v zero4(){ f4v z; z[0]=0.f; z[1]=0.f; z[2]=0.f; z[3]=0.f; return z; }
__device__ __forceinline__ void gload16(const unsigned short* g, unsigned short* l){
  __builtin_amdgcn_global_load_lds((const __attribute__((address_space(1))) unsigned int*)g,
                                   (__attribute__((address_space(3))) unsigned int*)l, 16, 0, 0);
}

// ---------------- prep: transpose+cast weights, zero denom ----------------
__global__ void k_prep(const float* __restrict__ wqkv, const float* __restrict__ wout,
                       unsigned short* __restrict__ wqkvT, unsigned short* __restrict__ woutT,
                       unsigned int* __restrict__ denomU){
  int t = blockIdx.x*256 + threadIdx.x;
  if (t == 0) denomU[0] = 0u;
  if (t < 786432){ int kk = t/1536, n = t%1536; wqkvT[(size_t)n*512 + kk] = f2b(wqkv[t]); }
  else { int t2 = t - 786432; if (t2 < 262144){ int kk = t2/512, n = t2%512; woutT[(size_t)n*512 + kk] = f2b(wout[t2]); } }
}

// ---------------- LayerNorm -> xn bf16 ----------------
__global__ __launch_bounds__(256) void k_ln(const float* __restrict__ x, const float* __restrict__ g,
                                            const float* __restrict__ be, unsigned short* __restrict__ xn){
  int row = blockIdx.x*4 + (threadIdx.x>>6);
  int l = threadIdx.x & 63;
  const float* xr = x + (size_t)row*DMODEL;
  float4 a = *(const float4*)(xr + l*4);
  float4 b = *(const float4*)(xr + 256 + l*4);
  float s = a.x+a.y+a.z+a.w + b.x+b.y+b.z+b.w;
  float q = a.x*a.x+a.y*a.y+a.z*a.z+a.w*a.w + b.x*b.x+b.y*b.y+b.z*b.z+b.w*b.w;
  #pragma unroll
  for (int m=1;m<64;m<<=1){ s += __shfl_xor(s,m); q += __shfl_xor(q,m); }
  float mean = s*(1.f/DMODEL);
  float rstd = rsqrtf(q*(1.f/DMODEL) - mean*mean + 1e-5f);
  int c0 = l*4, c1 = 256 + l*4;
  float av[4] = {a.x,a.y,a.z,a.w}, bv[4] = {b.x,b.y,b.z,b.w};
  ushort4 u0, u1;
  unsigned short* p0 = (unsigned short*)&u0; unsigned short* p1 = (unsigned short*)&u1;
  #pragma unroll
  for (int e=0;e<4;++e){
    p0[e] = f2b((av[e]-mean)*rstd*g[c0+e] + be[c0+e]);
    p1[e] = f2b((bv[e]-mean)*rstd*g[c1+e] + be[c1+e]);
  }
  *(ushort4*)(xn + (size_t)row*DMODEL + c0) = u0;
  *(ushort4*)(xn + (size_t)row*DMODEL + c1) = u1;
}

// ---------------- 128x128xK=512 GEMM core: global_load_lds staging, swizzled LDS ----------------
__device__ __forceinline__ void gemm512v2(const unsigned short* __restrict__ A, const unsigned short* __restrict__ B,
                                          int m0, int n0, int t, unsigned short* lA, unsigned short* lB,
                                          f4v acc[4][4]){
  int w = t>>6, l = t&63;
  int wm = (w&1)*64, wn = (w>>1)*64;
  int g = l>>4, qi = l&15;
  int rs = (w<<4) + (l>>2);
  int s0 = l&3;
  int c0 = ((s0 ^ ((rs>>1)&3)) << 3);
  int r1 = rs + 64;
  int c1 = ((s0 ^ ((r1>>1)&3)) << 3);
  const unsigned short* gA0 = A + (size_t)(m0+rs)*DMODEL + c0;
  const unsigned short* gA1 = A + (size_t)(m0+r1)*DMODEL + c1;
  const unsigned short* gB0 = B + (size_t)(n0+rs)*DMODEL + c0;
  const unsigned short* gB1 = B + (size_t)(n0+r1)*DMODEL + c1;
  unsigned short* dA0 = lA + (w<<9);
  unsigned short* dA1 = lA + 2048 + (w<<9);
  unsigned short* dB0 = lB + (w<<9);
  unsigned short* dB1 = lB + 2048 + (w<<9);
  int aofs[4], bofs[4];
  #pragma unroll
  for (int i=0;i<4;++i){
    int ra = wm + i*16 + qi;
    aofs[i] = ra*32 + ((g ^ ((ra>>1)&3))<<3);
    int rb = wn + i*16 + qi;
    bofs[i] = rb*32 + ((g ^ ((rb>>1)&3))<<3);
  }
  for (int ks=0; ks<16; ++ks){
    gload16(gA0, dA0); gload16(gA1, dA1);
    gload16(gB0, dB0); gload16(gB1, dB1);
    gA0 += 32; gA1 += 32; gB0 += 32; gB1 += 32;
    __syncthreads();
    s8v af[4], bf[4];
    #pragma unroll
    for (int i=0;i<4;++i) af[i] = *(s8v*)&lA[aofs[i]];
    #pragma unroll
    for (int j=0;j<4;++j) bf[j] = *(s8v*)&lB[bofs[j]];
    #pragma unroll
    for (int i=0;i<4;++i)
      #pragma unroll
      for (int j=0;j<4;++j) acc[i][j] = mfma16(af[i], bf[j], acc[i][j]);
    __syncthreads();
  }
}

// ---------------- QKV projection GEMM, XCD-swizzled block order, scatter epilogue (+vT) ----------------
__global__ __launch_bounds__(256) void k_gqkv(const unsigned short* __restrict__ xn, const unsigned short* __restrict__ wT,
                                              unsigned short* __restrict__ q, unsigned short* __restrict__ k,
                                              unsigned short* __restrict__ v, unsigned short* __restrict__ vT){
  __shared__ __align__(16) unsigned short lA[4096], lB[4096];
  int b0 = blockIdx.x;
  int bid = (b0 & 7) * 192 + (b0 >> 3);   // bijective: same-mblk blocks land on one XCD
  int mblk = bid/12, nblk = bid%12;
  int m0 = mblk*128, n0 = nblk*128;
  int t = threadIdx.x;
  f4v acc[4][4];
  #pragma unroll
  for (int i=0;i<4;++i)
    #pragma unroll
    for (int j=0;j<4;++j) acc[i][j] = zero4();
  gemm512v2(xn, wT, m0, n0, t, lA, lB, acc);
  int w = t>>6, l = t&63; int wm = (w&1)*64, wn = (w>>1)*64;
  int part = nblk >> 2;                 // 0=q 1=k 2=v
  int coff = (nblk & 3) * 128;
  unsigned short* dst = (part==0) ? q : (part==1) ? k : v;
  float scale = (part==0) ? 0.125f : 1.f;
  #pragma unroll
  for (int i=0;i<4;++i)
  #pragma unroll
  for (int j=0;j<4;++j){
    int colg = coff + wn + j*16 + (l&15);
    int h = colg>>6, c = colg&63;
    #pragma unroll
    for (int r=0;r<4;++r){
      int rowg = m0 + wm + i*16 + ((l>>4)<<2) + r;
      int b = rowg>>12, n = rowg&4095;
      unsigned short val = f2b(acc[i][j][r]*scale);
      dst[ (((size_t)(b*NHEAD + h))*SEQ + n)*DHEAD + c ] = val;
      if (part == 2)
        vT[ (((size_t)(b*NHEAD + h))*DHEAD + c)*SEQ + n ] = val;
    }
  }
}

// ---------------- output projection GEMM (+x +bias), XCD-swizzled ----------------
__global__ __launch_bounds__(256) void k_gout(const unsigned short* __restrict__ ao, const unsigned short* __restrict__ wT,
                                              const float* __restrict__ x, const float* __restrict__ bo,
                                              float* __restrict__ out){
  __shared__ __align__(16) unsigned short lA[4096], lB[4096];
  int b0 = blockIdx.x;
  int bid = (b0 & 7) * 64 + (b0 >> 3);
  int mblk = bid>>2, nblk = bid&3;
  int m0 = mblk*128, n0 = nblk*128;
  int t = threadIdx.x;
  f4v acc[4][4];
  #pragma unroll
  for (int i=0;i<4;++i)
    #pragma unroll
    for (int j=0;j<4;++j) acc[i][j] = zero4();
  gemm512v2(ao, wT, m0, n0, t, lA, lB, acc);
  int w = t>>6, l = t&63; int wm = (w&1)*64, wn = (w>>1)*64;
  #pragma unroll
  for (int i=0;i<4;++i)
  #pragma unroll
  for (int j=0;j<4;++j){
    int colg = n0 + wn + j*16 + (l&15);
    #pragma unroll
    for (int r=0;r<4;++r){
      int rowg = m0 + wm + i*16 + ((l>>4)<<2) + r;
      size_t ad = (size_t)rowg*DMODEL + colg;
      out[ad] = acc[i][j][r] + x[ad] + bo[colg];
    }
  }
}

// ---------------- landmark means (vectorized: 4 ch/thread) ----------------
__global__ void k_lmk(const unsigned short* __restrict__ q, const unsigned short* __restrict__ k,
                      unsigned short* __restrict__ ql, unsigned short* __restrict__ kl){
  int tg = blockIdx.x*256 + threadIdx.x;   // 131072 total
  int c4 = (tg&15)*4, m = (tg>>4)&255, bh = tg>>12;
  const unsigned short* qb = q + ((size_t)bh*SEQ + m*16)*DHEAD + c4;
  const unsigned short* kb = k + ((size_t)bh*SEQ + m*16)*DHEAD + c4;
  float s0=0.f,s1=0.f,s2=0.f,s3=0.f, t0=0.f,t1=0.f,t2=0.f,t3=0.f;
  #pragma unroll
  for (int j=0;j<16;++j){
    ushort4 uq = *(const ushort4*)(qb + (size_t)j*DHEAD);
    ushort4 uk = *(const ushort4*)(kb + (size_t)j*DHEAD);
    s0+=b2f(uq.x); s1+=b2f(uq.y); s2+=b2f(uq.z); s3+=b2f(uq.w);
    t0+=b2f(uk.x); t1+=b2f(uk.y); t2+=b2f(uk.z); t3+=b2f(uk.w);
  }
  ushort4 oq, ok;
  oq.x=f2b(s0*(1.f/16.f)); oq.y=f2b(s1*(1.f/16.f)); oq.z=f2b(s2*(1.f/16.f)); oq.w=f2b(s3*(1.f/16.f));
  ok.x=f2b(t0*(1.f/16.f)); ok.y=f2b(t1*(1.f/16.f)); ok.z=f2b(t2*(1.f/16.f)); ok.w=f2b(t3*(1.f/16.f));
  *(ushort4*)(ql + ((size_t)bh*NLM + m)*DHEAD + c4) = oq;
  *(ushort4*)(kl + ((size_t)bh*NLM + m)*DHEAD + c4) = ok;
}

// ---------------- attn2 = softmax(q_l k_l^T), store normal+T, colsum->denom ----------------
__global__ __launch_bounds__(512) void k_attn2(const unsigned short* __restrict__ ql, const unsigned short* __restrict__ kl,
                                               unsigned short* __restrict__ a2, unsigned short* __restrict__ a2t,
                                               unsigned int* __restrict__ denomU){
  __shared__ float cs[256];
  int bh = blockIdx.x; int t = threadIdx.x; int w = t>>6, l = t&63;
  const unsigned short* Q = ql + (size_t)bh*NLM*DHEAD;
  const unsigned short* K = kl + (size_t)bh*NLM*DHEAD;
  f4v acc[2][16];
  #pragma unroll
  for (int i=0;i<2;++i)
    #pragma unroll
    for (int j=0;j<16;++j) acc[i][j] = zero4();
  int m0 = w*32;
  #pragma unroll
  for (int ks=0; ks<2; ++ks){
    int kk = ks*32 + ((l>>4)<<3);
    s8v af0 = ldg8(&Q[(size_t)(m0 + (l&15))*DHEAD + kk]);
    s8v af1 = ldg8(&Q[(size_t)(m0 + 16 + (l&15))*DHEAD + kk]);
    #pragma unroll
    for (int j=0;j<16;++j){
      s8v bf = ldg8(&K[(size_t)(j*16 + (l&15))*DHEAD + kk]);
      acc[0][j] = mfma16(af0, bf, acc[0][j]);
      acc[1][j] = mfma16(af1, bf, acc[1][j]);
    }
  }
  #pragma unroll
  for (int i=0;i<2;++i)
  #pragma unroll
  for (int r=0;r<4;++r){
    float mx = -1e30f;
    #pragma unroll
    for (int j=0;j<16;++j) mx = fmaxf(mx, acc[i][j][r]);
    #pragma unroll
    for (int mm=1;mm<16;mm<<=1) mx = fmaxf(mx, __shfl_xor(mx,mm));
    float sm = 0.f;
    #pragma unroll
    for (int j=0;j<16;++j){ float p = __expf(acc[i][j][r]-mx); acc[i][j][r]=p; sm += p; }
    #pragma unroll
    for (int mm=1;mm<16;mm<<=1) sm += __shfl_xor(sm,mm);
    float inv = 1.f/sm;
    #pragma unroll
    for (int j=0;j<16;++j) acc[i][j][r] *= inv;
  }
  for (int e=t; e<256; e+=512) cs[e] = 0.f;
  __syncthreads();
  size_t b0 = (size_t)bh*NLM*NLM;
  #pragma unroll
  for (int i=0;i<2;++i)
  #pragma unroll
  for (int j=0;j<16;++j){
    int col = j*16 + (l&15);
    int rowb = m0 + i*16 + ((l>>4)<<2);
    float csp = 0.f;
    #pragma unroll
    for (int r=0;r<4;++r){
      float p = acc[i][j][r];
      unsigned short pb = f2b(p);
      a2 [b0 + (size_t)(rowb+r)*NLM + col] = pb;
      a2t[b0 + (size_t)col*NLM + rowb + r] = pb;
      csp += p;
    }
    csp += __shfl_xor(csp, 16); csp += __shfl_xor(csp, 32);
    if ((l>>4) == 0) atomicAdd(&cs[col], csp);
  }
  __syncthreads();
  if (t < 256) atomicMax(denomU, __float_as_uint(cs[t]));
}

// ---------------- attn3 @ v split-K partials: LDS-staged K/V (XOR-swizzled), 4 waves/block ----------------
__global__ __launch_bounds__(256) void k_a3w2p(const unsigned short* __restrict__ ql, const unsigned short* __restrict__ kb,
                                               const unsigned short* __restrict__ vT,
                                               float* __restrict__ po, float* __restrict__ pm, float* __restrict__ pd){
  __shared__ __align__(16) unsigned short Ks[256*64];
  __shared__ __align__(16) unsigned short Vs[64*256];
  int bid = blockIdx.x;
  int ksp = bid & 3;
  int qp  = (bid >> 2) & 3;
  int bh  = bid >> 4;
  int t = threadIdx.x, w = t>>6, l = t&63;
  int q0 = qp*64 + w*16;
  int g = l>>4, qi = l&15;
  const unsigned short* Q = ql + ((size_t)bh*NLM + q0)*DHEAD;
  const unsigned short* K = kb + (size_t)bh*SEQ*DHEAD;
  const unsigned short* V = vT + (size_t)bh*DHEAD*SEQ;
  s8v bq0 = ldg8(&Q[(size_t)qi*DHEAD + g*8]);
  s8v bq1 = ldg8(&Q[(size_t)qi*DHEAD + 32 + g*8]);
  float m_run = -1e30f, den = 0.f;
  f4v oacc[4];
  #pragma unroll
  for (int j=0;j<4;++j) oacc[j] = zero4();
  int sl0 = ((g&1)*2)*16 + qi;
  int jsel = g>>1;
  for (int kc = ksp*4; kc < ksp*4+4; ++kc){
    const unsigned short* Kc = K + (size_t)kc*256*DHEAD;
    #pragma unroll
    for (int it2=0; it2<8; ++it2){
      int cid = it2*256 + t;
      int row = cid>>3, cl = cid&7;
      gload16(&Kc[(size_t)(row<<6) + ((cl^(row&7))<<3)], Ks + it2*2048 + w*512);
      int row2 = cid>>5, cl2 = cid&31;
      gload16(&V[(size_t)row2*SEQ + kc*256 + ((cl2^(row2&7))<<3)], Vs + it2*2048 + 16384 - 16384 + w*512 + 0);
    }
    __syncthreads();
    f4v acc[16];
    #pragma unroll
    for (int j=0;j<16;++j) acc[j] = zero4();
    #pragma unroll
    for (int ks=0;ks<2;++ks){
      s8v bq = (ks==0) ? bq0 : bq1;
      #pragma unroll
      for (int j=0;j<16;++j){
        int r = j*16+qi;
        s8v ak = *(s8v*)&Ks[(size_t)(r<<6) + (((ks*4+g) ^ (qi&7))<<3)];
        acc[j] = mfma16(ak, bq, acc[j]);
      }
    }
    float cm = -1e30f;
    #pragma unroll
    for (int j=0;j<16;++j)
      cm = fmaxf(cm, fmaxf(fmaxf(acc[j][0],acc[j][1]), fmaxf(acc[j][2],acc[j][3])));
    cm = fmaxf(cm, __shfl_xor(cm,16));
    cm = fmaxf(cm, __shfl_xor(cm,32));
    float nm = fmaxf(m_run, cm);
    float f = __expf(m_run - nm);
    m_run = nm;
    float ls = 0.f;
    unsigned int pku[32];
    #pragma unroll
    for (int j=0;j<16;++j){
      float p0 = __expf(acc[j][0]-nm), p1 = __expf(acc[j][1]-nm);
      float p2 = __expf(acc[j][2]-nm), p3 = __expf(acc[j][3]-nm);
      ls += (p0+p1)+(p2+p3);
      pku[2*j+0] = (unsigned int)f2b(p0) | ((unsigned int)f2b(p1)<<16);
      pku[2*j+1] = (unsigned int)f2b(p2) | ((unsigned int)f2b(p3)<<16);
    }
    den = den*f + ls;
    float fr0 = __shfl(f, g*4+0, 64), fr1 = __shfl(f, g*4+1, 64);
    float fr2 = __shfl(f, g*4+2, 64), fr3 = __shfl(f, g*4+3, 64);
    #pragma unroll
    for (int j=0;j<4;++j){
      oacc[j][0]*=fr0; oacc[j][1]*=fr1; oacc[j][2]*=fr2; oacc[j][3]*=fr3;
    }
    #pragma unroll
    for (int ks=0;ks<8;++ks){
      unsigned int w0a = (unsigned int)__shfl((int)pku[4*ks+0], sl0, 64);
      unsigned int w1a = (unsigned int)__shfl((int)pku[4*ks+1], sl0, 64);
      unsigned int w0b = (unsigned int)__shfl((int)pku[4*ks+2], sl0, 64);
      unsigned int w1b = (unsigned int)__shfl((int)pku[4*ks+3], sl0, 64);
      unsigned int w2a = (unsigned int)__shfl((int)pku[4*ks+0], sl0+16, 64);
      unsigned int w3a = (unsigned int)__shfl((int)pku[4*ks+1], sl0+16, 64);
      unsigned int w2b = (unsigned int)__shfl((int)pku[4*ks+2], sl0+16, 64);
      unsigned int w3b = (unsigned int)__shfl((int)pku[4*ks+3], sl0+16, 64);
      unsigned int wv0 = jsel ? w0b : w0a;
      unsigned int wv1 = jsel ? w1b : w1a;
      unsigned int wv2 = jsel ? w2b : w2a;
      unsigned int wv3 = jsel ? w3b : w3a;
      s8v af;
      af[0] = (short)(wv0&0xffff); af[1] = (short)(wv0>>16);
      af[2] = (short)(wv1&0xffff); af[3] = (short)(wv1>>16);
      af[4] = (short)(wv2&0xffff); af[5] = (short)(wv2>>16);
      af[6] = (short)(wv3&0xffff); af[7] = (short)(wv3>>16);
      int ch = ks*4 + g;
      #pragma unroll
      for (int j=0;j<4;++j){
        int r = j*16+qi;
        s8v bu = *(s8v*)&Vs[(size_t)(r<<8) + ((ch ^ (qi&7))<<3)];
        oacc[j] = mfma16(af, bu, oacc[j]);
      }
    }
    __syncthreads();
  }
  den += __shfl_xor(den,16); den += __shfl_xor(den,32);
  #pragma unroll
  for (int j=0;j<4;++j)
    #pragma unroll
    for (int r=0;r<4;++r)
      po[(((size_t)(ksp*NBH + bh))*NLM + q0 + g*4 + r)*DHEAD + j*16 + qi] = oacc[j][r];
  if (g == 0){
    pm[(size_t)(ksp*NBH + bh)*NLM + q0 + qi] = m_run;
    pd[(size_t)(ksp*NBH + bh)*NLM + q0 + qi] = den;
  }
}

// ---------------- combine split-K partials -> w2t bf16 ----------------
__global__ __launch_bounds__(256) void k_a3c(const float* __restrict__ po, const float* __restrict__ pm,
                                             const float* __restrict__ pd, unsigned short* __restrict__ w2t){
  int tg = blockIdx.x*256 + threadIdx.x;   // 131072
  int bh = tg >> 12; int c = (tg >> 6) & 63; int r4 = (tg & 63) << 2;
  ushort4 ov;
  unsigned short* op = (unsigned short*)&ov;
  #pragma unroll
  for (int rr=0; rr<4; ++rr){
    int row = r4 + rr;
    float m[NSP];
    float gm = -1e30f;
    #pragma unroll
    for (int s=0;s<NSP;++s){ m[s] = pm[(size_t)(s*NBH+bh)*NLM + row]; gm = fmaxf(gm, m[s]); }
    float den = 0.f, o = 0.f;
    #pragma unroll
    for (int s=0;s<NSP;++s){
      float wsc = __expf(m[s]-gm);
      den += pd[(size_t)(s*NBH+bh)*NLM + row]*wsc;
      o   += po[(((size_t)(s*NBH+bh))*NLM + row)*DHEAD + c]*wsc;
    }
    op[rr] = f2b(o/den);
  }
  *(ushort4*)&w2t[(size_t)bh*DHEAD*NLM + (size_t)c*NLM + r4] = ov;
}

// ---------------- depthwise residual conv -> cf bf16 ----------------
__global__ __launch_bounds__(256) void k_conv(const unsigned short* __restrict__ v, const float* __restrict__ rw,
                                              unsigned short* __restrict__ cf){
  int bh = blockIdx.x >> 6;
  int n0 = (blockIdx.x & 63) * 64;
  int h = bh & 7, b = bh >> 3;
  int t = threadIdx.x;
  int tx = t & 15, ty = t >> 4;
  int c4 = tx * 4;
  int nb = n0 + ty * 4;
  const unsigned short* vb = v + ((size_t)bh * SEQ) * DHEAD + c4;
  ushort4 val[36];
  #pragma unroll
  for (int i = 0; i < 36; ++i){
    int nn = nb - 16 + i;
    if (nn >= 0 && nn < SEQ) val[i] = *(const ushort4*)(vb + (size_t)nn * DHEAD);
    else { val[i].x = 0; val[i].y = 0; val[i].z = 0; val[i].w = 0; }
  }
  float wgt[33];
  #pragma unroll
  for (int o = 0; o < 33; ++o) wgt[o] = rw[h*33 + o];
  #pragma unroll
  for (int i = 0; i < 4; ++i){
    float s0 = 0.f, s1 = 0.f, s2 = 0.f, s3 = 0.f;
    #pragma unroll
    for (int o = 0; o < 33; ++o){
      ushort4 u = val[i + o];
      float w0 = wgt[o];
      s0 += w0 * b2f(u.x); s1 += w0 * b2f(u.y);
      s2 += w0 * b2f(u.z); s3 += w0 * b2f(u.w);
    }
    ushort4 ov;
    ov.x = f2b(s0); ov.y = f2b(s1); ov.z = f2b(s2); ov.w = f2b(s3);
    size_t ad = ((size_t)b * SEQ + (nb + i)) * DMODEL + h * DHEAD + c4;
    *(ushort4*)(cf + ad) = ov;
  }
}

// ---------------- 64x64x256 single-wave MFMA core (R3-proven) ----------------
__device__ __forceinline__ void pcore(const unsigned short* __restrict__ Ab, const unsigned short* __restrict__ Bb,
                                      int m0, int n0, int l, f4v acc[4][4]){
  for (int ks=0; ks<8; ++ks){
    int kk = ks*32 + ((l>>4)<<3);
    s8v af[4], bf[4];
    #pragma unroll
    for (int i=0;i<4;++i) af[i] = ldg8(&Ab[(size_t)(m0 + i*16 + (l&15))*256 + kk]);
    #pragma unroll
    for (int j=0;j<4;++j) bf[j] = ldg8(&Bb[(size_t)(n0 + j*16 + (l&15))*256 + kk]);
    #pragma unroll
    for (int i=0;i<4;++i)
      #pragma unroll
      for (int j=0;j<4;++j) acc[i][j] = mfma16(af[i], bf[j], acc[i][j]);
  }
}

// ============ pinv via autonomous X-chain (R9-proven math, R12-proven kernel structure) ============
// X0 = a2@a2^T/d.  Per iter: L1{ Y=X@X (+CT=(7X-Y)^T) ; W=z@X (+E=7z-W) }
//                  L2{ X'=0.25(13X-15Y+Y@C) ; z'=0.25(13z-15W+E@Y) }
// z runs unscaled (linear chain); dinv folded into ue.

// X0: xz = a2 @ a2^T * dinv, dual store N+T (512 blocks x 64 thr)
__global__ __launch_bounds__(64) void k_x0(const unsigned short* __restrict__ a2,
                                           unsigned short* __restrict__ XN, unsigned short* __restrict__ XT,
                                           const unsigned int* __restrict__ denomU){
  int bid = blockIdx.x;
  int bh = bid>>4, tt = bid&15;
  int m0 = (tt>>2)*64, n0 = (tt&3)*64;
  int l = threadIdx.x;
  size_t bb = (size_t)bh*65536;
  f4v acc[4][4];
  #pragma unroll
  for (int i=0;i<4;++i)
    #pragma unroll
    for (int j=0;j<4;++j) acc[i][j] = zero4();
  pcore(a2+bb, a2+bb, m0, n0, l, acc);
  float s = 1.f/__uint_as_float(denomU[0]);
  #pragma unroll
  for (int i=0;i<4;++i)
  #pragma unroll
  for (int j=0;j<4;++j){
    int col = n0 + j*16 + (l&15);
    #pragma unroll
    for (int r=0;r<4;++r){
      int row = m0 + i*16 + ((l>>4)<<2) + r;
      unsigned short ob = f2b(acc[i][j][r]*s);
      XN[bb + (size_t)row*256 + col] = ob;
      XT[bb + (size_t)col*256 + row] = ob;
    }
  }
}

// L1 (1024 blocks x 64 thr): part0: Y=X@X -> YN,YT ; CT=(7X-Y)^T.  part1: W=z@X -> WN ; EN=7z-W
__global__ __launch_bounds__(64) void k_l1(const unsigned short* __restrict__ XN, const unsigned short* __restrict__ XT,
                                           const unsigned short* __restrict__ zsrc,
                                           unsigned short* __restrict__ YN, unsigned short* __restrict__ YT,
                                           unsigned short* __restrict__ CT,
                                           unsigned short* __restrict__ WN, unsigned short* __restrict__ EN){
  int bid = blockIdx.x;
  int part = bid>>9; bid &= 511;
  int bh = bid>>4, tt = bid&15;
  int m0 = (tt>>2)*64, n0 = (tt&3)*64;
  int l = threadIdx.x;
  size_t bb = (size_t)bh*65536;
  f4v acc[4][4];
  #pragma unroll
  for (int i=0;i<4;++i)
    #pragma unroll
    for (int j=0;j<4;++j) acc[i][j] = zero4();
  if (part == 0){
    pcore(XN+bb, XT+bb, m0, n0, l, acc);      // Y = X@X
    #pragma unroll
    for (int i=0;i<4;++i)
    #pragma unroll
    for (int j=0;j<4;++j){
      int col = n0 + j*16 + (l&15);
      #pragma unroll
      for (int r=0;r<4;++r){
        int row = m0 + i*16 + ((l>>4)<<2) + r;
        float y = acc[i][j][r];
        float xv = b2f(XN[bb + (size_t)row*256 + col]);
        unsigned short yb = f2b(y);
        YN[bb + (size_t)row*256 + col] = yb;
        YT[bb + (size_t)col*256 + row] = yb;
        CT[bb + (size_t)col*256 + row] = f2b(7.f*xv - y);
      }
    }
  } else {
    pcore(zsrc+bb, XT+bb, m0, n0, l, acc);    // W = z@X
    #pragma unroll
    for (int i=0;i<4;++i)
    #pragma unroll
    for (int j=0;j<4;++j){
      int col = n0 + j*16 + (l&15);
      #pragma unroll
      for (int r=0;r<4;++r){
        int row = m0 + i*16 + ((l>>4)<<2) + r;
        size_t idx = bb + (size_t)row*256 + col;
        float wv = acc[i][j][r];
        float zv = b2f(zsrc[idx]);
        WN[idx] = f2b(wv);
        EN[idx] = f2b(7.f*zv - wv);
      }
    }
  }
}

// L2 (1024 blocks, or 512 zonly): part0: X'=0.25(13X-15Y+Y@C) in-place. part1: z'=0.25(13z-15W+E@Y) -> zdst
__global__ __launch_bounds__(64) void k_l2(unsigned short* __restrict__ XN, unsigned short* __restrict__ XT,
                                           const unsigned short* __restrict__ zsrc, unsigned short* __restrict__ zdst,
                                           const unsigned short* __restrict__ YN, const unsigned short* __restrict__ YT,
                                           const unsigned short* __restrict__ CT,
                                           const unsigned short* __restrict__ WN, const unsigned short* __restrict__ EN,
                                           int zonly){
  int bid = blockIdx.x;
  int part;
  if (zonly){ part = 1; } else { part = bid>>9; bid &= 511; }
  int bh = bid>>4, tt = bid&15;
  int m0 = (tt>>2)*64, n0 = (tt&3)*64;
  int l = threadIdx.x;
  size_t bb = (size_t)bh*65536;
  f4v acc[4][4];
  #pragma unroll
  for (int i=0;i<4;++i)
    #pragma unroll
    for (int j=0;j<4;++j) acc[i][j] = zero4();
  if (part == 0){
    pcore(YN+bb, CT+bb, m0, n0, l, acc);      // Y@C
    #pragma unroll
    for (int i=0;i<4;++i)
    #pragma unroll
    for (int j=0;j<4;++j){
      int col = n0 + j*16 + (l&15);
      #pragma unroll
      for (int r=0;r<4;++r){
        int row = m0 + i*16 + ((l>>4)<<2) + r;
        size_t idx = bb + (size_t)row*256 + col;
        float xv = b2f(XN[idx]);
        float yv = b2f(YN[idx]);
        unsigned short ob = f2b(0.25f*(13.f*xv - 15.f*yv + acc[i][j][r]));
        XN[idx] = ob;
        XT[bb + (size_t)col*256 + row] = ob;
      }
    }
  } else {
    pcore(EN+bb, YT+bb, m0, n0, l, acc);      // E@Y
    #pragma unroll
    for (int i=0;i<4;++i)
    #pragma unroll
    for (int j=0;j<4;++j){
      int col = n0 + j*16 + (l&15);
      #pragma unroll
      for (int r=0;r<4;++r){
        int row = m0 + i*16 + ((l>>4)<<2) + r;
        size_t idx = bb + (size_t)row*256 + col;
        float zv = b2f(zsrc[idx]);
        float wv = b2f(WN[idx]);
        zdst[idx] = f2b(0.25f*(13.f*zv - 15.f*wv + acc[i][j][r]));
      }
    }
  }
}

// ue: uT = (z6 @ w2)^T * dinv   (128 blocks x 64 thr; pcore(z6, w2t) = z6 @ w2)
__global__ __launch_bounds__(64) void k_ue(const unsigned short* __restrict__ z6, const unsigned short* __restrict__ w2t,
                                           unsigned short* __restrict__ ut, const unsigned int* __restrict__ denomU){
  int bid = blockIdx.x;                 // bh*4 + mtile
  int bh = bid>>2, tt = bid&3;
  int m0 = tt*64;
  int l = threadIdx.x;
  float dinv = 1.f/__uint_as_float(denomU[0]);
  f4v acc[4][4];
  #pragma unroll
  for (int i=0;i<4;++i)
    #pragma unroll
    for (int j=0;j<4;++j) acc[i][j] = zero4();
  pcore(z6 + (size_t)bh*65536, w2t + (size_t)bh*16384, m0, 0, l, acc);
  #pragma unroll
  for (int i=0;i<4;++i)
  #pragma unroll
  for (int j=0;j<4;++j){
    int col = j*16 + (l&15);
    #pragma unroll
    for (int r=0;r<4;++r){
      int row = m0 + i*16 + ((l>>4)<<2) + r;
      ut[(size_t)bh*16384 + (size_t)col*256 + row] = f2b(acc[i][j][r]*dinv);
    }
  }
}

// ---------------- fused attn1: swapped QK^T, in-register softmax, shuffle P->A frags, @u, +conv ----------------
__global__ __launch_bounds__(256) void k_attn1(const unsigned short* __restrict__ qb, const unsigned short* __restrict__ kl,
                                               const unsigned short* __restrict__ ut, const unsigned short* __restrict__ cf,
                                               unsigned short* __restrict__ ao){
  int bh = blockIdx.x>>6;
  int t = threadIdx.x, w = t>>6, l = t&63;
  int q0 = ((blockIdx.x&63)<<6) + (w<<4);   // 16 q-rows per wave
  int g = l>>4, qi = l&15;
  const unsigned short* Q = qb + (size_t)bh*SEQ*DHEAD;
  const unsigned short* K = kl + (size_t)bh*NLM*DHEAD;
  f4v acc[16];
  #pragma unroll
  for (int j=0;j<16;++j) acc[j] = zero4();
  #pragma unroll
  for (int ks=0;ks<2;++ks){
    int kk = ks*32 + g*8;
    s8v bq = ldg8(&Q[(size_t)(q0+qi)*DHEAD + kk]);
    #pragma unroll
    for (int j=0;j<16;++j){
      s8v ak = ldg8(&K[(size_t)(j*16+qi)*DHEAD + kk]);
      acc[j] = mfma16(ak, bq, acc[j]);
    }
  }
  float mx = -1e30f;
  #pragma unroll
  for (int j=0;j<16;++j)
    mx = fmaxf(mx, fmaxf(fmaxf(acc[j][0],acc[j][1]), fmaxf(acc[j][2],acc[j][3])));
  mx = fmaxf(mx, __shfl_xor(mx,16));
  mx = fmaxf(mx, __shfl_xor(mx,32));
  float sm = 0.f;
  #pragma unroll
  for (int j=0;j<16;++j)
    #pragma unroll
    for (int r=0;r<4;++r){ float p = __expf(acc[j][r]-mx); acc[j][r]=p; sm += p; }
  sm += __shfl_xor(sm,16); sm += __shfl_xor(sm,32);
  float inv = 1.f/sm;
  unsigned int pku[32];
  #pragma unroll
  for (int j=0;j<16;++j){
    pku[2*j+0] = (unsigned int)f2b(acc[j][0]*inv) | ((unsigned int)f2b(acc[j][1]*inv)<<16);
    pku[2*j+1] = (unsigned int)f2b(acc[j][2]*inv) | ((unsigned int)f2b(acc[j][3]*inv)<<16);
  }
  const unsigned short* U = ut + (size_t)bh*DHEAD*NLM;
  f4v oacc[4];
  #pragma unroll
  for (int j=0;j<4;++j) oacc[j] = zero4();
  int sl0 = ((g&1)*2)*16 + qi;
  int jsel = g>>1;
  #pragma unroll
  for (int ks=0;ks<8;++ks){
    unsigned int w0a = (unsigned int)__shfl((int)pku[4*ks+0], sl0, 64);
    unsigned int w1a = (unsigned int)__shfl((int)pku[4*ks+1], sl0, 64);
    unsigned int w0b = (unsigned int)__shfl((int)pku[4*ks+2], sl0, 64);
    unsigned int w1b = (unsigned int)__shfl((int)pku[4*ks+3], sl0, 64);
    unsigned int w2a = (unsigned int)__shfl((int)pku[4*ks+0], sl0+16, 64);
    unsigned int w3a = (unsigned int)__shfl((int)pku[4*ks+1], sl0+16, 64);
    unsigned int w2b = (unsigned int)__shfl((int)pku[4*ks+2], sl0+16, 64);
    unsigned int w3b = (unsigned int)__shfl((int)pku[4*ks+3], sl0+16, 64);
    unsigned int wv0 = jsel ? w0b : w0a;
    unsigned int wv1 = jsel ? w1b : w1a;
    unsigned int wv2 = jsel ? w2b : w2a;
    unsigned int wv3 = jsel ? w3b : w3a;
    s8v af;
    af[0] = (short)(wv0&0xffff); af[1] = (short)(wv0>>16);
    af[2] = (short)(wv1&0xffff); af[3] = (short)(wv1>>16);
    af[4] = (short)(wv2&0xffff); af[5] = (short)(wv2>>16);
    af[6] = (short)(wv3&0xffff); af[7] = (short)(wv3>>16);
    int mk = ks*32 + g*8;
    #pragma unroll
    for (int j=0;j<4;++j){
      s8v bu = ldg8(&U[(size_t)(j*16+qi)*NLM + mk]);
      oacc[j] = mfma16(af, bu, oacc[j]);
    }
  }
  int b = bh>>3, h = bh&7;
  #pragma unroll
  for (int j=0;j<4;++j){
    int c = j*16 + qi;
    #pragma unroll
    for (int r=0;r<4;++r){
      int n = q0 + g*4 + r;
      size_t ad = ((size_t)(b*SEQ + n))*DMODEL + h*DHEAD + c;
      ao[ad] = f2b(oacc[j][r] + b2f(cf[ad]));
    }
  }
}

// =============================== host ===============================
extern "C" void kernel_launch(void* const* d_in, const int* in_sizes, int n_in,
                              void* d_out, int out_size, void* d_ws, size_t ws_size,
                              hipStream_t stream){
  const float* x    = (const float*)d_in[0];
  const float* lng  = (const float*)d_in[1];
  const float* lnb  = (const float*)d_in[2];
  const float* wqkv = (const float*)d_in[3];
  const float* wout = (const float*)d_in[4];
  const float* bout = (const float*)d_in[5];
  const float* resw = (const float*)d_in[6];
  float* out = (float*)d_out;

  char* ws = (char*)d_ws;
  size_t off = 0;
  auto alloc = [&](size_t bytes)->char*{ char* p = ws + off; off += (bytes + 255) & ~(size_t)255; return p; };

  unsigned short* wqkvT = (unsigned short*)alloc((size_t)1536*512*2);
  unsigned short* woutT = (unsigned short*)alloc((size_t)512*512*2);
  unsigned int*   denomU= (unsigned int*)  alloc(256);
  unsigned short* xn    = (unsigned short*)alloc((size_t)16384*512*2);   // 16 MB; later XN,XT,YN,YT (4x4MB)
  unsigned short* XN = xn;
  unsigned short* XT = xn + (size_t)1*NBH*NLM*NLM;
  unsigned short* YN = xn + (size_t)2*NBH*NLM*NLM;
  unsigned short* YT = xn + (size_t)3*NBH*NLM*NLM;
  unsigned short* q   = (unsigned short*)alloc((size_t)NBH*SEQ*DHEAD*2);
  unsigned short* kb  = (unsigned short*)alloc((size_t)NBH*SEQ*DHEAD*2);
  unsigned short* ao  = kb;  // alias: k dead before attn1
  unsigned short* v   = (unsigned short*)alloc((size_t)NBH*SEQ*DHEAD*2);
  unsigned short* vT  = (unsigned short*)alloc((size_t)NBH*DHEAD*SEQ*2);
  unsigned short* ql  = (unsigned short*)alloc((size_t)NBH*NLM*DHEAD*2);
  unsigned short* kl  = (unsigned short*)alloc((size_t)NBH*NLM*DHEAD*2);
  unsigned short* a2  = (unsigned short*)alloc((size_t)NBH*NLM*NLM*2);
  unsigned short* a2t = (unsigned short*)alloc((size_t)NBH*NLM*NLM*2);
  unsigned short* convf = (unsigned short*)alloc((size_t)NBAT*SEQ*DMODEL*2);
  unsigned short* CTb = (unsigned short*)alloc((size_t)NBH*NLM*NLM*2);
  unsigned short* WN  = (unsigned short*)alloc((size_t)NBH*NLM*NLM*2);
  unsigned short* EN  = (unsigned short*)alloc((size_t)NBH*NLM*NLM*2);
  unsigned short* zP  = (unsigned short*)alloc((size_t)NBH*NLM*NLM*2);
  unsigned short* zQ  = (unsigned short*)alloc((size_t)NBH*NLM*NLM*2);
  float* po = (float*)alloc((size_t)NSP*NBH*NLM*DHEAD*4);
  float* pm = (float*)alloc((size_t)NSP*NBH*NLM*4);
  float* pd = (float*)alloc((size_t)NSP*NBH*NLM*4);
  unsigned short* w2t = (unsigned short*)alloc((size_t)NBH*DHEAD*NLM*2);
  unsigned short* ut  = (unsigned short*)alloc((size_t)NBH*DHEAD*NLM*2);
  (void)ws_size; (void)in_sizes; (void)n_in; (void)out_size;

  k_prep<<<4096,256,0,stream>>>(wqkv, wout, wqkvT, woutT, denomU);
  k_ln  <<<4096,256,0,stream>>>(x, lng, lnb, xn);
  k_gqkv<<<1536,256,0,stream>>>(xn, wqkvT, q, kb, v, vT);
  k_lmk <<<512,256,0,stream>>>(q, kb, ql, kl);
  k_attn2<<<32,512,0,stream>>>(ql, kl, a2, a2t, denomU);
  k_a3w2p<<<512,256,0,stream>>>(ql, kb, vT, po, pm, pd);
  k_a3c <<<512,256,0,stream>>>(po, pm, pd, w2t);
  k_conv<<<2048,256,0,stream>>>(v, resw, convf);

  // pinv: autonomous X-chain (R9 math) in proven 64-thr pcore kernels; 14 launches
  // (xn dead now: XN/XT/YN/YT alias it)
  k_x0<<<512,64,0,stream>>>(a2, XN, XT, denomU);
  unsigned short* zbuf[2] = {zP, zQ};
  const unsigned short* zs = a2t;
  for (int it = 0; it < 6; ++it){
    int zonly = (it==5) ? 1 : 0;
    k_l1<<<1024,64,0,stream>>>(XN, XT, zs, YN, YT, CTb, WN, EN);
    k_l2<<<zonly?512:1024,64,0,stream>>>(XN, XT, zs, zbuf[it&1], YN, YT, CTb, WN, EN, zonly);
    zs = zbuf[it&1];
  }
  k_ue<<<128,64,0,stream>>>(zs, w2t, ut, denomU);

  k_attn1<<<2048,256,0,stream>>>(q, kl, ut, convf, ao);
  k_gout <<<512,256,0,stream>>>(ao, woutT, x, bout, out);
}

// Round 16
// 454.134 us; speedup vs baseline: 1.2474x; 1.2474x over previous
//
#include <hip/hip_runtime.h>
#include <hip/hip_bf16.h>

#define SEQ    4096
#define NBAT   4
#define NHEAD  8
#define NBH    32
#define DMODEL 512
#define DHEAD  64
#define NLM    256
#define NSP    4

typedef __attribute__((ext_vector_type(8))) short s8v;
typedef __attribute__((ext_vector_type(4))) float f4v;

__device__ __forceinline__ float b2f(unsigned short u){
  union { unsigned int i; float f; } v; v.i = ((unsigned int)u) << 16; return v.f;
}
__device__ __forceinline__ unsigned short f2b(float f){
  union { float f; unsigned int i; } v; v.f = f;
  unsigned int r = v.i + 0x7fffu + ((v.i >> 16) & 1u);
  return (unsigned short)(r >> 16);
}
__device__ __forceinline__ s8v ldg8(const unsigned short* p){
  return *reinterpret_cast<const s8v*>(p);
}
__device__ __forceinline__ f4v mfma16(s8v a, s8v b, f4v c){
  return __builtin_amdgcn_mfma_f32_16x16x32_bf16(a, b, c, 0, 0, 0);
}
__device__ __forceinline__ f4v zero4(){ f4v z; z[0]=0.f; z[1]=0.f; z[2]=0.f; z[3]=0.f; return z; }
__device__ __forceinline__ void gload16(const unsigned short* g, unsigned short* l){
  __builtin_amdgcn_global_load_lds((const __attribute__((address_space(1))) unsigned int*)g,
                                   (__attribute__((address_space(3))) unsigned int*)l, 16, 0, 0);
}

// ---------------- merged: prep (blocks 0..4095) + LayerNorm (blocks 4096..8191) ----------------
__global__ __launch_bounds__(256) void k_prepln(const float* __restrict__ wqkv, const float* __restrict__ wout,
                                                const float* __restrict__ x, const float* __restrict__ g,
                                                const float* __restrict__ be,
                                                unsigned short* __restrict__ wqkvT, unsigned short* __restrict__ woutT,
                                                unsigned short* __restrict__ xn, unsigned int* __restrict__ denomU){
  int b0 = blockIdx.x;
  if (b0 < 4096){
    int t = b0*256 + threadIdx.x;
    if (t == 0) denomU[0] = 0u;
    if (t < 786432){ int kk = t/1536, n = t%1536; wqkvT[(size_t)n*512 + kk] = f2b(wqkv[t]); }
    else { int t2 = t - 786432; if (t2 < 262144){ int kk = t2/512, n = t2%512; woutT[(size_t)n*512 + kk] = f2b(wout[t2]); } }
  } else {
    int row = (b0 - 4096)*4 + (threadIdx.x>>6);
    int l = threadIdx.x & 63;
    const float* xr = x + (size_t)row*DMODEL;
    float4 a = *(const float4*)(xr + l*4);
    float4 b = *(const float4*)(xr + 256 + l*4);
    float s = a.x+a.y+a.z+a.w + b.x+b.y+b.z+b.w;
    float q = a.x*a.x+a.y*a.y+a.z*a.z+a.w*a.w + b.x*b.x+b.y*b.y+b.z*b.z+b.w*b.w;
    #pragma unroll
    for (int m=1;m<64;m<<=1){ s += __shfl_xor(s,m); q += __shfl_xor(q,m); }
    float mean = s*(1.f/DMODEL);
    float rstd = rsqrtf(q*(1.f/DMODEL) - mean*mean + 1e-5f);
    int c0 = l*4, c1 = 256 + l*4;
    float av[4] = {a.x,a.y,a.z,a.w}, bv[4] = {b.x,b.y,b.z,b.w};
    ushort4 u0, u1;
    unsigned short* p0 = (unsigned short*)&u0; unsigned short* p1 = (unsigned short*)&u1;
    #pragma unroll
    for (int e=0;e<4;++e){
      p0[e] = f2b((av[e]-mean)*rstd*g[c0+e] + be[c0+e]);
      p1[e] = f2b((bv[e]-mean)*rstd*g[c1+e] + be[c1+e]);
    }
    *(ushort4*)(xn + (size_t)row*DMODEL + c0) = u0;
    *(ushort4*)(xn + (size_t)row*DMODEL + c1) = u1;
  }
}

// ---------------- 128x128xK=512 GEMM core: global_load_lds staging, swizzled LDS ----------------
__device__ __forceinline__ void gemm512v2(const unsigned short* __restrict__ A, const unsigned short* __restrict__ B,
                                          int m0, int n0, int t, unsigned short* lA, unsigned short* lB,
                                          f4v acc[4][4]){
  int w = t>>6, l = t&63;
  int wm = (w&1)*64, wn = (w>>1)*64;
  int g = l>>4, qi = l&15;
  int rs = (w<<4) + (l>>2);
  int s0 = l&3;
  int c0 = ((s0 ^ ((rs>>1)&3)) << 3);
  int r1 = rs + 64;
  int c1 = ((s0 ^ ((r1>>1)&3)) << 3);
  const unsigned short* gA0 = A + (size_t)(m0+rs)*DMODEL + c0;
  const unsigned short* gA1 = A + (size_t)(m0+r1)*DMODEL + c1;
  const unsigned short* gB0 = B + (size_t)(n0+rs)*DMODEL + c0;
  const unsigned short* gB1 = B + (size_t)(n0+r1)*DMODEL + c1;
  unsigned short* dA0 = lA + (w<<9);
  unsigned short* dA1 = lA + 2048 + (w<<9);
  unsigned short* dB0 = lB + (w<<9);
  unsigned short* dB1 = lB + 2048 + (w<<9);
  int aofs[4], bofs[4];
  #pragma unroll
  for (int i=0;i<4;++i){
    int ra = wm + i*16 + qi;
    aofs[i] = ra*32 + ((g ^ ((ra>>1)&3))<<3);
    int rb = wn + i*16 + qi;
    bofs[i] = rb*32 + ((g ^ ((rb>>1)&3))<<3);
  }
  for (int ks=0; ks<16; ++ks){
    gload16(gA0, dA0); gload16(gA1, dA1);
    gload16(gB0, dB0); gload16(gB1, dB1);
    gA0 += 32; gA1 += 32; gB0 += 32; gB1 += 32;
    __syncthreads();
    s8v af[4], bf[4];
    #pragma unroll
    for (int i=0;i<4;++i) af[i] = *(s8v*)&lA[aofs[i]];
    #pragma unroll
    for (int j=0;j<4;++j) bf[j] = *(s8v*)&lB[bofs[j]];
    #pragma unroll
    for (int i=0;i<4;++i)
      #pragma unroll
      for (int j=0;j<4;++j) acc[i][j] = mfma16(af[i], bf[j], acc[i][j]);
    __syncthreads();
  }
}

// ---------------- QKV projection GEMM, XCD-swizzled block order, scatter epilogue (+vT) ----------------
__global__ __launch_bounds__(256) void k_gqkv(const unsigned short* __restrict__ xn, const unsigned short* __restrict__ wT,
                                              unsigned short* __restrict__ q, unsigned short* __restrict__ k,
                                              unsigned short* __restrict__ v, unsigned short* __restrict__ vT){
  __shared__ __align__(16) unsigned short lA[4096], lB[4096];
  int b0 = blockIdx.x;
  int bid = (b0 & 7) * 192 + (b0 >> 3);   // bijective: same-mblk blocks land on one XCD
  int mblk = bid/12, nblk = bid%12;
  int m0 = mblk*128, n0 = nblk*128;
  int t = threadIdx.x;
  f4v acc[4][4];
  #pragma unroll
  for (int i=0;i<4;++i)
    #pragma unroll
    for (int j=0;j<4;++j) acc[i][j] = zero4();
  gemm512v2(xn, wT, m0, n0, t, lA, lB, acc);
  int w = t>>6, l = t&63; int wm = (w&1)*64, wn = (w>>1)*64;
  int part = nblk >> 2;                 // 0=q 1=k 2=v
  int coff = (nblk & 3) * 128;
  unsigned short* dst = (part==0) ? q : (part==1) ? k : v;
  float scale = (part==0) ? 0.125f : 1.f;
  #pragma unroll
  for (int i=0;i<4;++i)
  #pragma unroll
  for (int j=0;j<4;++j){
    int colg = coff + wn + j*16 + (l&15);
    int h = colg>>6, c = colg&63;
    #pragma unroll
    for (int r=0;r<4;++r){
      int rowg = m0 + wm + i*16 + ((l>>4)<<2) + r;
      int b = rowg>>12, n = rowg&4095;
      unsigned short val = f2b(acc[i][j][r]*scale);
      dst[ (((size_t)(b*NHEAD + h))*SEQ + n)*DHEAD + c ] = val;
      if (part == 2)
        vT[ (((size_t)(b*NHEAD + h))*DHEAD + c)*SEQ + n ] = val;
    }
  }
}

// ---------------- output projection GEMM (+x +bias), XCD-swizzled ----------------
__global__ __launch_bounds__(256) void k_gout(const unsigned short* __restrict__ ao, const unsigned short* __restrict__ wT,
                                              const float* __restrict__ x, const float* __restrict__ bo,
                                              float* __restrict__ out){
  __shared__ __align__(16) unsigned short lA[4096], lB[4096];
  int b0 = blockIdx.x;
  int bid = (b0 & 7) * 64 + (b0 >> 3);
  int mblk = bid>>2, nblk = bid&3;
  int m0 = mblk*128, n0 = nblk*128;
  int t = threadIdx.x;
  f4v acc[4][4];
  #pragma unroll
  for (int i=0;i<4;++i)
    #pragma unroll
    for (int j=0;j<4;++j) acc[i][j] = zero4();
  gemm512v2(ao, wT, m0, n0, t, lA, lB, acc);
  int w = t>>6, l = t&63; int wm = (w&1)*64, wn = (w>>1)*64;
  #pragma unroll
  for (int i=0;i<4;++i)
  #pragma unroll
  for (int j=0;j<4;++j){
    int colg = n0 + wn + j*16 + (l&15);
    #pragma unroll
    for (int r=0;r<4;++r){
      int rowg = m0 + wm + i*16 + ((l>>4)<<2) + r;
      size_t ad = (size_t)rowg*DMODEL + colg;
      out[ad] = acc[i][j][r] + x[ad] + bo[colg];
    }
  }
}

// ---------------- merged: conv (blocks 0..2047) + landmark means (blocks 2048..2559) ----------------
__global__ __launch_bounds__(256) void k_cvlmk(const unsigned short* __restrict__ q, const unsigned short* __restrict__ k,
                                               const unsigned short* __restrict__ v, const float* __restrict__ rw,
                                               unsigned short* __restrict__ cf,
                                               unsigned short* __restrict__ ql, unsigned short* __restrict__ kl){
  int blk = blockIdx.x;
  if (blk < 2048){
    int bh = blk >> 6;
    int n0 = (blk & 63) * 64;
    int h = bh & 7, b = bh >> 3;
    int t = threadIdx.x;
    int tx = t & 15, ty = t >> 4;
    int c4 = tx * 4;
    int nb = n0 + ty * 4;
    const unsigned short* vb = v + ((size_t)bh * SEQ) * DHEAD + c4;
    ushort4 val[36];
    #pragma unroll
    for (int i = 0; i < 36; ++i){
      int nn = nb - 16 + i;
      if (nn >= 0 && nn < SEQ) val[i] = *(const ushort4*)(vb + (size_t)nn * DHEAD);
      else { val[i].x = 0; val[i].y = 0; val[i].z = 0; val[i].w = 0; }
    }
    float wgt[33];
    #pragma unroll
    for (int o = 0; o < 33; ++o) wgt[o] = rw[h*33 + o];
    #pragma unroll
    for (int i = 0; i < 4; ++i){
      float s0 = 0.f, s1 = 0.f, s2 = 0.f, s3 = 0.f;
      #pragma unroll
      for (int o = 0; o < 33; ++o){
        ushort4 u = val[i + o];
        float w0 = wgt[o];
        s0 += w0 * b2f(u.x); s1 += w0 * b2f(u.y);
        s2 += w0 * b2f(u.z); s3 += w0 * b2f(u.w);
      }
      ushort4 ov;
      ov.x = f2b(s0); ov.y = f2b(s1); ov.z = f2b(s2); ov.w = f2b(s3);
      size_t ad = ((size_t)b * SEQ + (nb + i)) * DMODEL + h * DHEAD + c4;
      *(ushort4*)(cf + ad) = ov;
    }
  } else {
    int tg = (blk - 2048)*256 + threadIdx.x;   // 131072 total
    int c4 = (tg&15)*4, m = (tg>>4)&255, bh = tg>>12;
    const unsigned short* qb = q + ((size_t)bh*SEQ + m*16)*DHEAD + c4;
    const unsigned short* kb = k + ((size_t)bh*SEQ + m*16)*DHEAD + c4;
    float s0=0.f,s1=0.f,s2=0.f,s3=0.f, t0=0.f,t1=0.f,t2=0.f,t3=0.f;
    #pragma unroll
    for (int j=0;j<16;++j){
      ushort4 uq = *(const ushort4*)(qb + (size_t)j*DHEAD);
      ushort4 uk = *(const ushort4*)(kb + (size_t)j*DHEAD);
      s0+=b2f(uq.x); s1+=b2f(uq.y); s2+=b2f(uq.z); s3+=b2f(uq.w);
      t0+=b2f(uk.x); t1+=b2f(uk.y); t2+=b2f(uk.z); t3+=b2f(uk.w);
    }
    ushort4 oq, ok;
    oq.x=f2b(s0*(1.f/16.f)); oq.y=f2b(s1*(1.f/16.f)); oq.z=f2b(s2*(1.f/16.f)); oq.w=f2b(s3*(1.f/16.f));
    ok.x=f2b(t0*(1.f/16.f)); ok.y=f2b(t1*(1.f/16.f)); ok.z=f2b(t2*(1.f/16.f)); ok.w=f2b(t3*(1.f/16.f));
    *(ushort4*)(ql + ((size_t)bh*NLM + m)*DHEAD + c4) = oq;
    *(ushort4*)(kl + ((size_t)bh*NLM + m)*DHEAD + c4) = ok;
  }
}

// ---------------- attn2 = softmax(q_l k_l^T), store normal+T, colsum->denom ----------------
__global__ __launch_bounds__(512) void k_attn2(const unsigned short* __restrict__ ql, const unsigned short* __restrict__ kl,
                                               unsigned short* __restrict__ a2, unsigned short* __restrict__ a2t,
                                               unsigned int* __restrict__ denomU){
  __shared__ float cs[256];
  int bh = blockIdx.x; int t = threadIdx.x; int w = t>>6, l = t&63;
  const unsigned short* Q = ql + (size_t)bh*NLM*DHEAD;
  const unsigned short* K = kl + (size_t)bh*NLM*DHEAD;
  f4v acc[2][16];
  #pragma unroll
  for (int i=0;i<2;++i)
    #pragma unroll
    for (int j=0;j<16;++j) acc[i][j] = zero4();
  int m0 = w*32;
  #pragma unroll
  for (int ks=0; ks<2; ++ks){
    int kk = ks*32 + ((l>>4)<<3);
    s8v af0 = ldg8(&Q[(size_t)(m0 + (l&15))*DHEAD + kk]);
    s8v af1 = ldg8(&Q[(size_t)(m0 + 16 + (l&15))*DHEAD + kk]);
    #pragma unroll
    for (int j=0;j<16;++j){
      s8v bf = ldg8(&K[(size_t)(j*16 + (l&15))*DHEAD + kk]);
      acc[0][j] = mfma16(af0, bf, acc[0][j]);
      acc[1][j] = mfma16(af1, bf, acc[1][j]);
    }
  }
  #pragma unroll
  for (int i=0;i<2;++i)
  #pragma unroll
  for (int r=0;r<4;++r){
    float mx = -1e30f;
    #pragma unroll
    for (int j=0;j<16;++j) mx = fmaxf(mx, acc[i][j][r]);
    #pragma unroll
    for (int mm=1;mm<16;mm<<=1) mx = fmaxf(mx, __shfl_xor(mx,mm));
    float sm = 0.f;
    #pragma unroll
    for (int j=0;j<16;++j){ float p = __expf(acc[i][j][r]-mx); acc[i][j][r]=p; sm += p; }
    #pragma unroll
    for (int mm=1;mm<16;mm<<=1) sm += __shfl_xor(sm,mm);
    float inv = 1.f/sm;
    #pragma unroll
    for (int j=0;j<16;++j) acc[i][j][r] *= inv;
  }
  for (int e=t; e<256; e+=512) cs[e] = 0.f;
  __syncthreads();
  size_t b0 = (size_t)bh*NLM*NLM;
  #pragma unroll
  for (int i=0;i<2;++i)
  #pragma unroll
  for (int j=0;j<16;++j){
    int col = j*16 + (l&15);
    int rowb = m0 + i*16 + ((l>>4)<<2);
    float csp = 0.f;
    #pragma unroll
    for (int r=0;r<4;++r){
      float p = acc[i][j][r];
      unsigned short pb = f2b(p);
      a2 [b0 + (size_t)(rowb+r)*NLM + col] = pb;
      a2t[b0 + (size_t)col*NLM + rowb + r] = pb;
      csp += p;
    }
    csp += __shfl_xor(csp, 16); csp += __shfl_xor(csp, 32);
    if ((l>>4) == 0) atomicAdd(&cs[col], csp);
  }
  __syncthreads();
  if (t < 256) atomicMax(denomU, __float_as_uint(cs[t]));
}

// ---------------- attn3 @ v split-K partials: LDS-staged K/V (XOR-swizzled), 4 waves/block ----------------
__global__ __launch_bounds__(256) void k_a3w2p(const unsigned short* __restrict__ ql, const unsigned short* __restrict__ kb,
                                               const unsigned short* __restrict__ vT,
                                               float* __restrict__ po, float* __restrict__ pm, float* __restrict__ pd){
  __shared__ __align__(16) unsigned short Ks[256*64];
  __shared__ __align__(16) unsigned short Vs[64*256];
  int bid = blockIdx.x;
  int ksp = bid & 3;
  int qp  = (bid >> 2) & 3;
  int bh  = bid >> 4;
  int t = threadIdx.x, w = t>>6, l = t&63;
  int q0 = qp*64 + w*16;
  int g = l>>4, qi = l&15;
  const unsigned short* Q = ql + ((size_t)bh*NLM + q0)*DHEAD;
  const unsigned short* K = kb + (size_t)bh*SEQ*DHEAD;
  const unsigned short* V = vT + (size_t)bh*DHEAD*SEQ;
  s8v bq0 = ldg8(&Q[(size_t)qi*DHEAD + g*8]);
  s8v bq1 = ldg8(&Q[(size_t)qi*DHEAD + 32 + g*8]);
  float m_run = -1e30f, den = 0.f;
  f4v oacc[4];
  #pragma unroll
  for (int j=0;j<4;++j) oacc[j] = zero4();
  int sl0 = ((g&1)*2)*16 + qi;
  int jsel = g>>1;
  for (int kc = ksp*4; kc < ksp*4+4; ++kc){
    const unsigned short* Kc = K + (size_t)kc*256*DHEAD;
    #pragma unroll
    for (int it2=0; it2<8; ++it2){
      int cid = it2*256 + t;
      int row = cid>>3, cl = cid&7;
      gload16(&Kc[(size_t)(row<<6) + ((cl^(row&7))<<3)], Ks + it2*2048 + w*512);
      int row2 = cid>>5, cl2 = cid&31;
      gload16(&V[(size_t)row2*SEQ + kc*256 + ((cl2^(row2&7))<<3)], Vs + it2*2048 + w*512);
    }
    __syncthreads();
    f4v acc[16];
    #pragma unroll
    for (int j=0;j<16;++j) acc[j] = zero4();
    #pragma unroll
    for (int ks=0;ks<2;++ks){
      s8v bq = (ks==0) ? bq0 : bq1;
      #pragma unroll
      for (int j=0;j<16;++j){
        int r = j*16+qi;
        s8v ak = *(s8v*)&Ks[(size_t)(r<<6) + (((ks*4+g) ^ (qi&7))<<3)];
        acc[j] = mfma16(ak, bq, acc[j]);
      }
    }
    float cm = -1e30f;
    #pragma unroll
    for (int j=0;j<16;++j)
      cm = fmaxf(cm, fmaxf(fmaxf(acc[j][0],acc[j][1]), fmaxf(acc[j][2],acc[j][3])));
    cm = fmaxf(cm, __shfl_xor(cm,16));
    cm = fmaxf(cm, __shfl_xor(cm,32));
    float nm = fmaxf(m_run, cm);
    float f = __expf(m_run - nm);
    m_run = nm;
    float ls = 0.f;
    unsigned int pku[32];
    #pragma unroll
    for (int j=0;j<16;++j){
      float p0 = __expf(acc[j][0]-nm), p1 = __expf(acc[j][1]-nm);
      float p2 = __expf(acc[j][2]-nm), p3 = __expf(acc[j][3]-nm);
      ls += (p0+p1)+(p2+p3);
      pku[2*j+0] = (unsigned int)f2b(p0) | ((unsigned int)f2b(p1)<<16);
      pku[2*j+1] = (unsigned int)f2b(p2) | ((unsigned int)f2b(p3)<<16);
    }
    den = den*f + ls;
    float fr0 = __shfl(f, g*4+0, 64), fr1 = __shfl(f, g*4+1, 64);
    float fr2 = __shfl(f, g*4+2, 64), fr3 = __shfl(f, g*4+3, 64);
    #pragma unroll
    for (int j=0;j<4;++j){
      oacc[j][0]*=fr0; oacc[j][1]*=fr1; oacc[j][2]*=fr2; oacc[j][3]*=fr3;
    }
    #pragma unroll
    for (int ks=0;ks<8;++ks){
      unsigned int w0a = (unsigned int)__shfl((int)pku[4*ks+0], sl0, 64);
      unsigned int w1a = (unsigned int)__shfl((int)pku[4*ks+1], sl0, 64);
      unsigned int w0b = (unsigned int)__shfl((int)pku[4*ks+2], sl0, 64);
      unsigned int w1b = (unsigned int)__shfl((int)pku[4*ks+3], sl0, 64);
      unsigned int w2a = (unsigned int)__shfl((int)pku[4*ks+0], sl0+16, 64);
      unsigned int w3a = (unsigned int)__shfl((int)pku[4*ks+1], sl0+16, 64);
      unsigned int w2b = (unsigned int)__shfl((int)pku[4*ks+2], sl0+16, 64);
      unsigned int w3b = (unsigned int)__shfl((int)pku[4*ks+3], sl0+16, 64);
      unsigned int wv0 = jsel ? w0b : w0a;
      unsigned int wv1 = jsel ? w1b : w1a;
      unsigned int wv2 = jsel ? w2b : w2a;
      unsigned int wv3 = jsel ? w3b : w3a;
      s8v af;
      af[0] = (short)(wv0&0xffff); af[1] = (short)(wv0>>16);
      af[2] = (short)(wv1&0xffff); af[3] = (short)(wv1>>16);
      af[4] = (short)(wv2&0xffff); af[5] = (short)(wv2>>16);
      af[6] = (short)(wv3&0xffff); af[7] = (short)(wv3>>16);
      int ch = ks*4 + g;
      #pragma unroll
      for (int j=0;j<4;++j){
        int r = j*16+qi;
        s8v bu = *(s8v*)&Vs[(size_t)(r<<8) + ((ch ^ (qi&7))<<3)];
        oacc[j] = mfma16(af, bu, oacc[j]);
      }
    }
    __syncthreads();
  }
  den += __shfl_xor(den,16); den += __shfl_xor(den,32);
  #pragma unroll
  for (int j=0;j<4;++j)
    #pragma unroll
    for (int r=0;r<4;++r)
      po[(((size_t)(ksp*NBH + bh))*NLM + q0 + g*4 + r)*DHEAD + j*16 + qi] = oacc[j][r];
  if (g == 0){
    pm[(size_t)(ksp*NBH + bh)*NLM + q0 + qi] = m_run;
    pd[(size_t)(ksp*NBH + bh)*NLM + q0 + qi] = den;
  }
}

// ---------------- combine split-K partials -> w2t bf16 ----------------
__global__ __launch_bounds__(256) void k_a3c(const float* __restrict__ po, const float* __restrict__ pm,
                                             const float* __restrict__ pd, unsigned short* __restrict__ w2t){
  int tg = blockIdx.x*256 + threadIdx.x;   // 131072
  int bh = tg >> 12; int c = (tg >> 6) & 63; int r4 = (tg & 63) << 2;
  ushort4 ov;
  unsigned short* op = (unsigned short*)&ov;
  #pragma unroll
  for (int rr=0; rr<4; ++rr){
    int row = r4 + rr;
    float m[NSP];
    float gm = -1e30f;
    #pragma unroll
    for (int s=0;s<NSP;++s){ m[s] = pm[(size_t)(s*NBH+bh)*NLM + row]; gm = fmaxf(gm, m[s]); }
    float den = 0.f, o = 0.f;
    #pragma unroll
    for (int s=0;s<NSP;++s){
      float wsc = __expf(m[s]-gm);
      den += pd[(size_t)(s*NBH+bh)*NLM + row]*wsc;
      o   += po[(((size_t)(s*NBH+bh))*NLM + row)*DHEAD + c]*wsc;
    }
    op[rr] = f2b(o/den);
  }
  *(ushort4*)&w2t[(size_t)bh*DHEAD*NLM + (size_t)c*NLM + r4] = ov;
}

// ---------------- 64x64x256 single-wave MFMA core (R3-proven) ----------------
__device__ __forceinline__ void pcore(const unsigned short* __restrict__ Ab, const unsigned short* __restrict__ Bb,
                                      int m0, int n0, int l, f4v acc[4][4]){
  for (int ks=0; ks<8; ++ks){
    int kk = ks*32 + ((l>>4)<<3);
    s8v af[4], bf[4];
    #pragma unroll
    for (int i=0;i<4;++i) af[i] = ldg8(&Ab[(size_t)(m0 + i*16 + (l&15))*256 + kk]);
    #pragma unroll
    for (int j=0;j<4;++j) bf[j] = ldg8(&Bb[(size_t)(n0 + j*16 + (l&15))*256 + kk]);
    #pragma unroll
    for (int i=0;i<4;++i)
      #pragma unroll
      for (int j=0;j<4;++j) acc[i][j] = mfma16(af[i], bf[j], acc[i][j]);
  }
}

// ---------------- pinv stage 1: xz = a2 @ z (write N+T) ----------------
__global__ __launch_bounds__(64) void k_pg1(const unsigned short* __restrict__ A, const unsigned short* __restrict__ BT,
                                            unsigned short* __restrict__ oN, unsigned short* __restrict__ oT,
                                            int sdiv, const unsigned int* __restrict__ denomU){
  int bid = blockIdx.x;
  int bh = bid>>4, tt = bid&15;
  int m0 = (tt>>2)*64, n0 = (tt&3)*64;
  int l = threadIdx.x;
  const unsigned short* Ab = A + (size_t)bh*65536;
  const unsigned short* Bb = BT + (size_t)bh*65536;
  f4v acc[4][4];
  #pragma unroll
  for (int i=0;i<4;++i)
    #pragma unroll
    for (int j=0;j<4;++j) acc[i][j] = zero4();
  pcore(Ab, Bb, m0, n0, l, acc);
  float s = sdiv ? 1.f/__uint_as_float(denomU[0]) : 1.f;
  #pragma unroll
  for (int i=0;i<4;++i)
  #pragma unroll
  for (int j=0;j<4;++j){
    int col = n0 + j*16 + (l&15);
    #pragma unroll
    for (int r=0;r<4;++r){
      int row = m0 + i*16 + ((l>>4)<<2) + r;
      unsigned short ob = f2b(acc[i][j][r]*s);
      oN[(size_t)bh*65536 + (size_t)row*256 + col] = ob;
      oT[(size_t)bh*65536 + (size_t)col*256 + row] = ob;
    }
  }
}

// ---------------- pinv stage 2 (batched): CT = (7*xz - xz@xz)^T ; PN = z @ xz ----------------
__global__ __launch_bounds__(64) void k_pg2(const unsigned short* __restrict__ xzN, const unsigned short* __restrict__ xzT,
                                            const unsigned short* __restrict__ zsrc,
                                            unsigned short* __restrict__ CT, unsigned short* __restrict__ PN,
                                            int sdiv, const unsigned int* __restrict__ denomU){
  int bid = blockIdx.x;
  int part = bid>>9; bid &= 511;
  int bh = bid>>4, tt = bid&15;
  int m0 = (tt>>2)*64, n0 = (tt&3)*64;
  int l = threadIdx.x;
  const unsigned short* Ab = (part==0 ? xzN : zsrc) + (size_t)bh*65536;
  const unsigned short* Bb = xzT + (size_t)bh*65536;
  f4v acc[4][4];
  #pragma unroll
  for (int i=0;i<4;++i)
    #pragma unroll
    for (int j=0;j<4;++j) acc[i][j] = zero4();
  pcore(Ab, Bb, m0, n0, l, acc);
  if (part == 0){
    #pragma unroll
    for (int i=0;i<4;++i)
    #pragma unroll
    for (int j=0;j<4;++j){
      int col = n0 + j*16 + (l&15);
      #pragma unroll
      for (int r=0;r<4;++r){
        int row = m0 + i*16 + ((l>>4)<<2) + r;
        float xv = b2f(xzN[(size_t)bh*65536 + (size_t)row*256 + col]);
        CT[(size_t)bh*65536 + (size_t)col*256 + row] = f2b(7.f*xv - acc[i][j][r]);
      }
    }
  } else {
    float s = sdiv ? 1.f/__uint_as_float(denomU[0]) : 1.f;
    #pragma unroll
    for (int i=0;i<4;++i)
    #pragma unroll
    for (int j=0;j<4;++j){
      int col = n0 + j*16 + (l&15);
      #pragma unroll
      for (int r=0;r<4;++r){
        int row = m0 + i*16 + ((l>>4)<<2) + r;
        PN[(size_t)bh*65536 + (size_t)row*256 + col] = f2b(acc[i][j][r]*s);
      }
    }
  }
}

// ---------------- pinv stage 3: z' = 0.25*(13 z - 15 P + P@C), write N+T ----------------
__global__ __launch_bounds__(64) void k_pg3(const unsigned short* __restrict__ PN, const unsigned short* __restrict__ CT,
                                            const unsigned short* __restrict__ zsrc,
                                            unsigned short* __restrict__ zN, unsigned short* __restrict__ zT,
                                            int sdiv, const unsigned int* __restrict__ denomU){
  int bid = blockIdx.x;
  int bh = bid>>4, tt = bid&15;
  int m0 = (tt>>2)*64, n0 = (tt&3)*64;
  int l = threadIdx.x;
  const unsigned short* Ab = PN + (size_t)bh*65536;
  const unsigned short* Bb = CT + (size_t)bh*65536;
  f4v acc[4][4];
  #pragma unroll
  for (int i=0;i<4;++i)
    #pragma unroll
    for (int j=0;j<4;++j) acc[i][j] = zero4();
  pcore(Ab, Bb, m0, n0, l, acc);
  float zs = sdiv ? 1.f/__uint_as_float(denomU[0]) : 1.f;
  #pragma unroll
  for (int i=0;i<4;++i)
  #pragma unroll
  for (int j=0;j<4;++j){
    int col = n0 + j*16 + (l&15);
    #pragma unroll
    for (int r=0;r<4;++r){
      int row = m0 + i*16 + ((l>>4)<<2) + r;
      float zv = b2f(zsrc[(size_t)bh*65536 + (size_t)row*256 + col])*zs;
      float pv = b2f(PN  [(size_t)bh*65536 + (size_t)row*256 + col]);
      float res = 0.25f*(13.f*zv - 15.f*pv + acc[i][j][r]);
      unsigned short ob = f2b(res);
      zN[(size_t)bh*65536 + (size_t)row*256 + col] = ob;
      zT[(size_t)bh*65536 + (size_t)col*256 + row] = ob;
    }
  }
}

// ---------------- generic batched 64x64-tile GEMM (u = z6 @ w2, store T) ----------------
template<bool WN, bool WT>
__global__ __launch_bounds__(64) void k_pgemm(
    const unsigned short* __restrict__ A, const unsigned short* __restrict__ BT,
    unsigned short* __restrict__ oN, unsigned short* __restrict__ oT,
    int mt, int nt, long strA, long strBT, long strON, long strOT)
{
  int bid = blockIdx.x;
  int nper = mt*nt;
  int bh = bid/nper, tt = bid%nper;
  int m0 = (tt/nt)*64, n0 = (tt%nt)*64;
  const unsigned short* Ab = A + (size_t)bh*strA;
  const unsigned short* Bb = BT + (size_t)bh*strBT;
  int l = threadIdx.x;
  f4v acc[4][4];
  #pragma unroll
  for (int i=0;i<4;++i)
    #pragma unroll
    for (int j=0;j<4;++j) acc[i][j] = zero4();
  pcore(Ab, Bb, m0, n0, l, acc);
  #pragma unroll
  for (int i=0;i<4;++i)
  #pragma unroll
  for (int j=0;j<4;++j){
    int col = n0 + j*16 + (l&15);
    #pragma unroll
    for (int r=0;r<4;++r){
      int row = m0 + i*16 + ((l>>4)<<2) + r;
      unsigned short ob = f2b(acc[i][j][r]);
      if constexpr (WN) oN[(size_t)bh*strON + (size_t)row*256 + col] = ob;
      if constexpr (WT) oT[(size_t)bh*strOT + (size_t)col*256 + row] = ob;
    }
  }
}

// ---------------- fused attn1: swapped QK^T, in-register softmax, shuffle P->A frags, @u, +conv ----------------
__global__ __launch_bounds__(256) void k_attn1(const unsigned short* __restrict__ qb, const unsigned short* __restrict__ kl,
                                               const unsigned short* __restrict__ ut, const unsigned short* __restrict__ cf,
                                               unsigned short* __restrict__ ao){
  int bh = blockIdx.x>>6;
  int t = threadIdx.x, w = t>>6, l = t&63;
  int q0 = ((blockIdx.x&63)<<6) + (w<<4);   // 16 q-rows per wave
  int g = l>>4, qi = l&15;
  const unsigned short* Q = qb + (size_t)bh*SEQ*DHEAD;
  const unsigned short* K = kl + (size_t)bh*NLM*DHEAD;
  f4v acc[16];
  #pragma unroll
  for (int j=0;j<16;++j) acc[j] = zero4();
  #pragma unroll
  for (int ks=0;ks<2;++ks){
    int kk = ks*32 + g*8;
    s8v bq = ldg8(&Q[(size_t)(q0+qi)*DHEAD + kk]);
    #pragma unroll
    for (int j=0;j<16;++j){
      s8v ak = ldg8(&K[(size_t)(j*16+qi)*DHEAD + kk]);
      acc[j] = mfma16(ak, bq, acc[j]);
    }
  }
  float mx = -1e30f;
  #pragma unroll
  for (int j=0;j<16;++j)
    mx = fmaxf(mx, fmaxf(fmaxf(acc[j][0],acc[j][1]), fmaxf(acc[j][2],acc[j][3])));
  mx = fmaxf(mx, __shfl_xor(mx,16));
  mx = fmaxf(mx, __shfl_xor(mx,32));
  float sm = 0.f;
  #pragma unroll
  for (int j=0;j<16;++j)
    #pragma unroll
    for (int r=0;r<4;++r){ float p = __expf(acc[j][r]-mx); acc[j][r]=p; sm += p; }
  sm += __shfl_xor(sm,16); sm += __shfl_xor(sm,32);
  float inv = 1.f/sm;
  unsigned int pku[32];
  #pragma unroll
  for (int j=0;j<16;++j){
    pku[2*j+0] = (unsigned int)f2b(acc[j][0]*inv) | ((unsigned int)f2b(acc[j][1]*inv)<<16);
    pku[2*j+1] = (unsigned int)f2b(acc[j][2]*inv) | ((unsigned int)f2b(acc[j][3]*inv)<<16);
  }
  const unsigned short* U = ut + (size_t)bh*DHEAD*NLM;
  f4v oacc[4];
  #pragma unroll
  for (int j=0;j<4;++j) oacc[j] = zero4();
  int sl0 = ((g&1)*2)*16 + qi;
  int jsel = g>>1;
  #pragma unroll
  for (int ks=0;ks<8;++ks){
    unsigned int w0a = (unsigned int)__shfl((int)pku[4*ks+0], sl0, 64);
    unsigned int w1a = (unsigned int)__shfl((int)pku[4*ks+1], sl0, 64);
    unsigned int w0b = (unsigned int)__shfl((int)pku[4*ks+2], sl0, 64);
    unsigned int w1b = (unsigned int)__shfl((int)pku[4*ks+3], sl0, 64);
    unsigned int w2a = (unsigned int)__shfl((int)pku[4*ks+0], sl0+16, 64);
    unsigned int w3a = (unsigned int)__shfl((int)pku[4*ks+1], sl0+16, 64);
    unsigned int w2b = (unsigned int)__shfl((int)pku[4*ks+2], sl0+16, 64);
    unsigned int w3b = (unsigned int)__shfl((int)pku[4*ks+3], sl0+16, 64);
    unsigned int wv0 = jsel ? w0b : w0a;
    unsigned int wv1 = jsel ? w1b : w1a;
    unsigned int wv2 = jsel ? w2b : w2a;
    unsigned int wv3 = jsel ? w3b : w3a;
    s8v af;
    af[0] = (short)(wv0&0xffff); af[1] = (short)(wv0>>16);
    af[2] = (short)(wv1&0xffff); af[3] = (short)(wv1>>16);
    af[4] = (short)(wv2&0xffff); af[5] = (short)(wv2>>16);
    af[6] = (short)(wv3&0xffff); af[7] = (short)(wv3>>16);
    int mk = ks*32 + g*8;
    #pragma unroll
    for (int j=0;j<4;++j){
      s8v bu = ldg8(&U[(size_t)(j*16+qi)*NLM + mk]);
      oacc[j] = mfma16(af, bu, oacc[j]);
    }
  }
  int b = bh>>3, h = bh&7;
  #pragma unroll
  for (int j=0;j<4;++j){
    int c = j*16 + qi;
    #pragma unroll
    for (int r=0;r<4;++r){
      int n = q0 + g*4 + r;
      size_t ad = ((size_t)(b*SEQ + n))*DMODEL + h*DHEAD + c;
      ao[ad] = f2b(oacc[j][r] + b2f(cf[ad]));
    }
  }
}

// =============================== host ===============================
extern "C" void kernel_launch(void* const* d_in, const int* in_sizes, int n_in,
                              void* d_out, int out_size, void* d_ws, size_t ws_size,
                              hipStream_t stream){
  const float* x    = (const float*)d_in[0];
  const float* lng  = (const float*)d_in[1];
  const float* lnb  = (const float*)d_in[2];
  const float* wqkv = (const float*)d_in[3];
  const float* wout = (const float*)d_in[4];
  const float* bout = (const float*)d_in[5];
  const float* resw = (const float*)d_in[6];
  float* out = (float*)d_out;

  char* ws = (char*)d_ws;
  size_t off = 0;
  auto alloc = [&](size_t bytes)->char*{ char* p = ws + off; off += (bytes + 255) & ~(size_t)255; return p; };

  unsigned short* wqkvT = (unsigned short*)alloc((size_t)1536*512*2);
  unsigned short* woutT = (unsigned short*)alloc((size_t)512*512*2);
  unsigned int*   denomU= (unsigned int*)  alloc(256);
  unsigned short* xn    = (unsigned short*)alloc((size_t)16384*512*2);   // 16 MB; later zA,zAT,zB,zBT (4x4MB)
  unsigned short* zA  = xn;
  unsigned short* zAT = xn + (size_t)1*NBH*NLM*NLM;
  unsigned short* zB  = xn + (size_t)2*NBH*NLM*NLM;
  unsigned short* zBT = xn + (size_t)3*NBH*NLM*NLM;
  unsigned short* q   = (unsigned short*)alloc((size_t)NBH*SEQ*DHEAD*2);
  unsigned short* kb  = (unsigned short*)alloc((size_t)NBH*SEQ*DHEAD*2);
  unsigned short* ao  = kb;  // alias: k dead before attn1
  unsigned short* v   = (unsigned short*)alloc((size_t)NBH*SEQ*DHEAD*2);
  unsigned short* vT  = (unsigned short*)alloc((size_t)NBH*DHEAD*SEQ*2);
  unsigned short* ql  = (unsigned short*)alloc((size_t)NBH*NLM*DHEAD*2);
  unsigned short* kl  = (unsigned short*)alloc((size_t)NBH*NLM*DHEAD*2);
  unsigned short* a2  = (unsigned short*)alloc((size_t)NBH*NLM*NLM*2);
  unsigned short* a2t = (unsigned short*)alloc((size_t)NBH*NLM*NLM*2);
  unsigned short* convf = (unsigned short*)alloc((size_t)NBAT*SEQ*DMODEL*2);
  unsigned short* xzN = (unsigned short*)alloc((size_t)NBH*NLM*NLM*2);
  unsigned short* xzT = (unsigned short*)alloc((size_t)NBH*NLM*NLM*2);
  unsigned short* pn  = (unsigned short*)alloc((size_t)NBH*NLM*NLM*2);
  unsigned short* ctb = (unsigned short*)alloc((size_t)NBH*NLM*NLM*2);
  float* po = (float*)alloc((size_t)NSP*NBH*NLM*DHEAD*4);
  float* pm = (float*)alloc((size_t)NSP*NBH*NLM*4);
  float* pd = (float*)alloc((size_t)NSP*NBH*NLM*4);
  unsigned short* w2t = (unsigned short*)alloc((size_t)NBH*DHEAD*NLM*2);
  unsigned short* ut  = (unsigned short*)alloc((size_t)NBH*DHEAD*NLM*2);
  (void)ws_size; (void)in_sizes; (void)n_in; (void)out_size;

  k_prepln<<<8192,256,0,stream>>>(wqkv, wout, x, lng, lnb, wqkvT, woutT, xn, denomU);
  k_gqkv<<<1536,256,0,stream>>>(xn, wqkvT, q, kb, v, vT);
  k_cvlmk<<<2560,256,0,stream>>>(q, kb, v, resw, convf, ql, kl);
  k_attn2<<<32,512,0,stream>>>(ql, kl, a2, a2t, denomU);
  k_a3w2p<<<512,256,0,stream>>>(ql, kb, vT, po, pm, pd);
  k_a3c <<<512,256,0,stream>>>(po, pm, pd, w2t);

  // asymmetric pinv chain: R3-proven 64-thread kernels (xn dead now, z buffers alias it)
  unsigned short* zN_[2] = {zA, zB};
  unsigned short* zT_[2] = {zAT, zBT};
  for (int it = 0; it < 6; ++it){
    const unsigned short* BT   = (it==0) ? a2  : zT_[(it-1)&1];   // z^T row-major
    const unsigned short* zsrc = (it==0) ? a2t : zN_[(it-1)&1];   // z row-major
    int sdiv = (it==0) ? 1 : 0;
    k_pg1<<<512 ,64,0,stream>>>(a2, BT, xzN, xzT, sdiv, denomU);
    k_pg2<<<1024,64,0,stream>>>(xzN, xzT, zsrc, ctb, pn, sdiv, denomU);
    k_pg3<<<512 ,64,0,stream>>>(pn, ctb, zsrc, zN_[it&1], zT_[it&1], sdiv, denomU);
  }
  // uT = (z6 @ w2)^T
  k_pgemm<false,true><<<128,64,0,stream>>>(zN_[1], w2t, (unsigned short*)nullptr, ut, 4,1, 65536L,16384L,0L,16384L);

  k_attn1<<<2048,256,0,stream>>>(q, kl, ut, convf, ao);
  k_gout <<<512,256,0,stream>>>(ao, woutT, x, bout, out);
}